// Round 12
// baseline (194.551 us; speedup 1.0000x reference)
//
#include <hip/hip_runtime.h>
#include <hip/hip_bf16.h>

typedef unsigned short u16;
typedef __attribute__((ext_vector_type(8))) short short8;
typedef __attribute__((ext_vector_type(4))) float floatx4;

#define NROWS 8192
#define DIM 256

__device__ __forceinline__ void atomicMinFloat(float* addr, float val) {
    if (val >= 0.0f) {
        atomicMin((int*)addr, __float_as_int(val));
    } else {
        atomicMax((unsigned int*)addr, __float_as_uint(val));
    }
}

__device__ __forceinline__ u16 f32_to_bf16_rne(float x) {
    unsigned int u = __float_as_uint(x);
    unsigned int r = (u + 0x7fffu + ((u >> 16) & 1u)) >> 16;
    return (u16)r;
}

// C(M) = -logp * exp(logp); quasiconcave in M => rowmin = min(C(minM), C(maxM)).
__device__ __forceinline__ float c_of_m(float m) {
    const float INV_SIG = 1.0f / 0.3f;
    const float KC = 0.28503427f;  // -ln(0.3) - 0.5*ln(2*pi)
    float z = (m - 1.0f) * INV_SIG;
    float logp = fmaf(-0.5f * z, z, KC);
    return -logp * __expf(logp);
}

// 16B async DMA global -> LDS. LDS dest is wave-uniform base + lane*16.
__device__ __forceinline__ void load16(const u16* g, u16* l) {
    __builtin_amdgcn_global_load_lds(
        (__attribute__((address_space(1))) void*)g,
        (__attribute__((address_space(3))) void*)l, 16, 0, 0);
}

// Normalize rows (L2-norm clamped at 1e-8), wave per row, float4 loads.
// BOTH X and Y are written in MFMA fragment ("panel") layout:
//   element (row r, k) -> flat[ ((p*8+kt)*64 + lq*16 + lm)*8 + j ]
//   p=r>>4, lm=r&15, kt=k>>5, lq=(k>>3)&3, j=k&7.
// A fragment load is then base + lane*16B: one coalesced dwordx4.
// Verified end-to-end R5/R11 (absmax 1.5e-5).
__global__ __launch_bounds__(256) void normalize_kernel(const float* __restrict__ Ex,
                                                        const float* __restrict__ Ey,
                                                        u16* __restrict__ Xs,
                                                        u16* __restrict__ Ys,
                                                        float* __restrict__ out) {
    const int t = threadIdx.x;
    const int ln = t & 63;
    const int row = blockIdx.x * 4 + (t >> 6);
    const float* src = (blockIdx.y == 0) ? Ex : Ey;
    u16* dst = (blockIdx.y == 0) ? Xs : Ys;

    float4 v = *(const float4*)(src + (size_t)row * DIM + ln * 4);
    float s = fmaf(v.x, v.x, fmaf(v.y, v.y, fmaf(v.z, v.z, v.w * v.w)));
    #pragma unroll
    for (int m = 32; m >= 1; m >>= 1) s += __shfl_xor(s, m, 64);
    float inv = 1.0f / fmaxf(sqrtf(s), 1e-8f);

    ushort4 o;
    o.x = f32_to_bf16_rne(v.x * inv);
    o.y = f32_to_bf16_rne(v.y * inv);
    o.z = f32_to_bf16_rne(v.z * inv);
    o.w = f32_to_bf16_rne(v.w * inv);

    const int p = row >> 4;
    const int lm = row & 15;
    const int kt = ln >> 3;
    const int lq = (ln >> 1) & 3;
    const int j4 = (ln & 1) * 4;
    const size_t off = ((size_t)((p * 8 + kt) * 64 + lq * 16 + lm)) * 8 + j4;
    *(ushort4*)(dst + off) = o;

    if (blockIdx.y == 0 && ln == 0) out[row] = __uint_as_float(0x7f800000u);  // +inf
}

// Block = 256 rows x 512 cols, 8 waves (4 row-groups x 2 col-groups),
// wave tile 64x64 (R11 micro-structure unchanged).
// A: each wave's 64 rows x full K from panel-layout Xs into registers
//    (L2-resident, coalesced dwordx4) -- no A LDS traffic.
// B: half-K (128k x 128cols = 32 KB) LDS chunks, double-buffered, DMA-staged
//    (R11 mechanics; 8 waves stage 4 units each). 8 drains per block.
// vs R11: 2x rows per block => staged-B bytes per CU and drain rounds per CU
// both HALVE (0.5 MB, 16) for the same MFMA work -- attacking the quantity
// R6/R11 share at their common 50 us plateau.
// Grid 512: b&31 = row-tile (fixed A per XCD), b>>5 = colgroup.
__global__ void __launch_bounds__(512, 4)
gemm_min_kernel(const u16* __restrict__ Xs,
                const u16* __restrict__ Ys,
                float* __restrict__ out) {
    __shared__ u16 Bs[2][32 * 512];  // 2 x 32 KB

    const int tid = threadIdx.x;
    const int w = tid >> 6;      // 0..7
    const int lane = tid & 63;
    const int wr = w >> 1;       // 0..3 row-group
    const int wc = w & 1;        // 0..1 col-group
    const int lq = lane >> 4;
    const int lm = lane & 15;

    const int b = blockIdx.x;
    const int rowStart = (b & 31) * 256;
    const int rowPan0 = (b & 31) * 16 + wr * 4;
    const u16* ybase = Ys + (size_t)((b >> 5) * 32) * 4096;  // advances 32768/ct

    // --- A into registers, once (32 coalesced dwordx4 per lane) ---
    short8 a[4][8];
    #pragma unroll
    for (int rg = 0; rg < 4; ++rg)
        #pragma unroll
        for (int kt = 0; kt < 8; ++kt)
            a[rg][kt] = *(const short8*)(Xs + ((size_t)(rowPan0 + rg) * 8 + kt) * 512 + lane * 8);

    floatx4 mn4[4], mx4[4];
    #pragma unroll
    for (int rg = 0; rg < 4; ++rg) {
        mn4[rg] = (floatx4){3.4e38f, 3.4e38f, 3.4e38f, 3.4e38f};
        mx4[rg] = (floatx4){-3.4e38f, -3.4e38f, -3.4e38f, -3.4e38f};
    }

    // Stage one 32 KB B half-K chunk (8 panels x 4 kt-units of 1 KB) via DMA.
    // 8 waves stage 4 units each; unit u = (panel u>>2, kt u&3).
    auto stageB = [&](int buf, const u16* yb, int h) {
        #pragma unroll
        for (int i = 0; i < 4; ++i) {
            const int u = w * 4 + i;
            load16(yb + (u >> 2) * 4096 + (h * 4 + (u & 3)) * 512 + lane * 8,
                   &Bs[buf][u * 512]);
        }
    };

    stageB(0, ybase, 0);  // prologue: (ct=0, half 0)

    #pragma unroll 1
    for (int ct = 0; ct < 4; ++ct) {
        floatx4 acc[4][4];
        #pragma unroll
        for (int i = 0; i < 4; ++i)
            #pragma unroll
            for (int j = 0; j < 4; ++j)
                acc[i][j] = (floatx4){0.0f, 0.0f, 0.0f, 0.0f};

        // One half-K body: 4 kt x 4 cg B-frag ds_reads (b128, lane-contiguous
        // = conflict-free) x 4 rg MFMAs from the register-resident A array.
        auto compHalf = [&](int buf, int h) {
            #pragma unroll
            for (int kt = 0; kt < 4; ++kt) {
                #pragma unroll
                for (int cg = 0; cg < 4; ++cg) {
                    short8 bf = *(const short8*)(
                        &Bs[buf][(wc * 16 + cg * 4 + kt) * 512 + lane * 8]);
                    #pragma unroll
                    for (int rg = 0; rg < 4; ++rg)
                        acc[rg][cg] = __builtin_amdgcn_mfma_f32_16x16x32_bf16(
                            a[rg][h * 4 + kt], bf, acc[rg][cg], 0, 0, 0);
                }
            }
        };

        __syncthreads();           // drains (ct, h=0) DMA
        stageB(1, ybase, 1);       // prefetch (ct, h=1) into buf 1
        compHalf(0, 0);

        __syncthreads();           // drains (ct, h=1) DMA; all reads of buf0 done
        if (ct < 3)
            stageB(0, ybase + 32768, 0);  // prefetch (ct+1, h=0) into buf 0
        compHalf(1, 1);

        // Fold this col-tile into register-carried row min/max.
        #pragma unroll
        for (int rg = 0; rg < 4; ++rg)
            #pragma unroll
            for (int cg = 0; cg < 4; ++cg)
                #pragma unroll
                for (int r = 0; r < 4; ++r) {
                    float m = acc[rg][cg][r];
                    mn4[rg][r] = fminf(mn4[rg][r], m);
                    mx4[rg][r] = fmaxf(mx4[rg][r], m);
                }

        ybase += 32768;  // loop-carried: blocks cross-ct hoisting
    }

    // Single epilogue: quad-lane reduce, eval C twice (quasiconcavity),
    // fire-and-forget atomicMin (no read guard -- R3 post-mortem).
    #pragma unroll
    for (int rg = 0; rg < 4; ++rg) {
        #pragma unroll
        for (int r = 0; r < 4; ++r) {
            float mn = mn4[rg][r];
            float mx = mx4[rg][r];
            #pragma unroll
            for (int mofs = 1; mofs < 16; mofs <<= 1) {
                mn = fminf(mn, __shfl_xor(mn, mofs, 64));
                mx = fmaxf(mx, __shfl_xor(mx, mofs, 64));
            }
            if (lm == 0) {
                float cmin = fminf(c_of_m(mn), c_of_m(mx));
                int row = rowStart + wr * 64 + rg * 16 + lq * 4 + r;
                atomicMinFloat(&out[row], cmin);
            }
        }
    }
}

extern "C" void kernel_launch(void* const* d_in, const int* in_sizes, int n_in,
                              void* d_out, int out_size, void* d_ws, size_t ws_size,
                              hipStream_t stream) {
    const float* Ex = (const float*)d_in[0];
    const float* Ey = (const float*)d_in[1];
    float* out = (float*)d_out;
    u16* Xs = (u16*)d_ws;                // 4 MB, panel layout
    u16* Ys = Xs + (size_t)NROWS * DIM;  // 4 MB, panel layout

    hipLaunchKernelGGL(normalize_kernel, dim3(NROWS / 4, 2), dim3(256), 0, stream,
                       Ex, Ey, Xs, Ys, out);
    hipLaunchKernelGGL(gemm_min_kernel, dim3(32 * 16), dim3(512), 0, stream,
                       Xs, Ys, out);
}

// Round 13
// 104.294 us; speedup vs baseline: 1.8654x; 1.8654x over previous
//
#include <hip/hip_runtime.h>
#include <hip/hip_bf16.h>

typedef unsigned short u16;
typedef __attribute__((ext_vector_type(8))) short short8;
typedef __attribute__((ext_vector_type(4))) float floatx4;

#define NROWS 8192
#define DIM 256

__device__ __forceinline__ void atomicMinFloat(float* addr, float val) {
    if (val >= 0.0f) {
        atomicMin((int*)addr, __float_as_int(val));
    } else {
        atomicMax((unsigned int*)addr, __float_as_uint(val));
    }
}

__device__ __forceinline__ u16 f32_to_bf16_rne(float x) {
    unsigned int u = __float_as_uint(x);
    unsigned int r = (u + 0x7fffu + ((u >> 16) & 1u)) >> 16;
    return (u16)r;
}

// C(M) = -logp * exp(logp); quasiconcave in M => rowmin = min(C(minM), C(maxM)).
__device__ __forceinline__ float c_of_m(float m) {
    const float INV_SIG = 1.0f / 0.3f;
    const float KC = 0.28503427f;  // -ln(0.3) - 0.5*ln(2*pi)
    float z = (m - 1.0f) * INV_SIG;
    float logp = fmaf(-0.5f * z, z, KC);
    return -logp * __expf(logp);
}

// 16B async DMA global -> LDS. LDS dest is wave-uniform base + lane*16.
__device__ __forceinline__ void load16(const u16* g, u16* l) {
    __builtin_amdgcn_global_load_lds(
        (__attribute__((address_space(1))) void*)g,
        (__attribute__((address_space(3))) void*)l, 16, 0, 0);
}

// Normalize rows (L2-norm clamped at 1e-8), wave per row, float4 loads.
// BOTH X and Y are written in MFMA fragment ("panel") layout:
//   element (row r, k) -> flat[ ((p*8+kt)*64 + lq*16 + lm)*8 + j ]
//   p=r>>4, lm=r&15, kt=k>>5, lq=(k>>3)&3, j=k&7.
// A fragment load is then base + lane*16B: one coalesced dwordx4.
// Verified end-to-end R5/R11 (absmax 1.5e-5).
__global__ __launch_bounds__(256) void normalize_kernel(const float* __restrict__ Ex,
                                                        const float* __restrict__ Ey,
                                                        u16* __restrict__ Xs,
                                                        u16* __restrict__ Ys,
                                                        float* __restrict__ out) {
    const int t = threadIdx.x;
    const int ln = t & 63;
    const int row = blockIdx.x * 4 + (t >> 6);
    const float* src = (blockIdx.y == 0) ? Ex : Ey;
    u16* dst = (blockIdx.y == 0) ? Xs : Ys;

    float4 v = *(const float4*)(src + (size_t)row * DIM + ln * 4);
    float s = fmaf(v.x, v.x, fmaf(v.y, v.y, fmaf(v.z, v.z, v.w * v.w)));
    #pragma unroll
    for (int m = 32; m >= 1; m >>= 1) s += __shfl_xor(s, m, 64);
    float inv = 1.0f / fmaxf(sqrtf(s), 1e-8f);

    ushort4 o;
    o.x = f32_to_bf16_rne(v.x * inv);
    o.y = f32_to_bf16_rne(v.y * inv);
    o.z = f32_to_bf16_rne(v.z * inv);
    o.w = f32_to_bf16_rne(v.w * inv);

    const int p = row >> 4;
    const int lm = row & 15;
    const int kt = ln >> 3;
    const int lq = (ln >> 1) & 3;
    const int j4 = (ln & 1) * 4;
    const size_t off = ((size_t)((p * 8 + kt) * 64 + lq * 16 + lm)) * 8 + j4;
    *(ushort4*)(dst + off) = o;

    if (blockIdx.y == 0 && ln == 0) out[row] = __uint_as_float(0x7f800000u);  // +inf
}

// Block = 128 rows x 512 cols, 4 waves (2x2, wave tile 64x64). R11 structure:
// A register-resident (panel-layout Xs, loaded once); B via DMA-staged
// half-K LDS chunks (32 KB, double-buffered, 8 barriers/block).
// R13 change: compHalf is hand-pipelined -- B fragments for k-step kt+1 are
// loaded into the alternate named register group BEFORE kt's 16 MFMAs, so
// each 4x ds_read_b128 batch has ~310 cyc of MFMA cover (vs ~78 in R11's
// load-use pattern). 8 b128 in flight at each half start.
// Grid: b&63 = row-tile (fixed A per XCD), b>>6 = colgroup (shared B strip).
__global__ void __launch_bounds__(256, 2)
gemm_min_kernel(const u16* __restrict__ Xs,
                const u16* __restrict__ Ys,
                float* __restrict__ out) {
    __shared__ u16 Bs[2][32 * 512];  // 2 x 32 KB

    const int tid = threadIdx.x;
    const int w = tid >> 6;
    const int lane = tid & 63;
    const int wr = w >> 1;
    const int wc = w & 1;
    const int lq = lane >> 4;
    const int lm = lane & 15;

    const int b = blockIdx.x;
    const int rowStart = (b & 63) * 128;
    const int rowPan0 = (b & 63) * 8 + wr * 4;
    const u16* ybase = Ys + (size_t)((b >> 6) * 32) * 4096;  // advances 32768/ct

    // --- A into registers, once (32 coalesced dwordx4 per lane) ---
    short8 a[4][8];
    #pragma unroll
    for (int rg = 0; rg < 4; ++rg)
        #pragma unroll
        for (int kt = 0; kt < 8; ++kt)
            a[rg][kt] = *(const short8*)(Xs + ((size_t)(rowPan0 + rg) * 8 + kt) * 512 + lane * 8);

    floatx4 mn4[4], mx4[4];
    #pragma unroll
    for (int rg = 0; rg < 4; ++rg) {
        mn4[rg] = (floatx4){3.4e38f, 3.4e38f, 3.4e38f, 3.4e38f};
        mx4[rg] = (floatx4){-3.4e38f, -3.4e38f, -3.4e38f, -3.4e38f};
    }

    // Stage one 32 KB B half-K chunk (8 panels x 4 kt-units of 1 KB) via DMA.
    // Wave w stages units u = w*8 .. w*8+7; unit u = (panel u>>2, kt u&3).
    auto stageB = [&](int buf, const u16* yb, int h) {
        #pragma unroll
        for (int i = 0; i < 8; ++i) {
            const int u = w * 8 + i;
            load16(yb + (u >> 2) * 4096 + (h * 4 + (u & 3)) * 512 + lane * 8,
                   &Bs[buf][u * 512]);
        }
    };

    stageB(0, ybase, 0);  // prologue: (ct=0, half 0)

    #pragma unroll 1
    for (int ct = 0; ct < 4; ++ct) {
        floatx4 acc[4][4];
        #pragma unroll
        for (int i = 0; i < 4; ++i)
            #pragma unroll
            for (int j = 0; j < 4; ++j)
                acc[i][j] = (floatx4){0.0f, 0.0f, 0.0f, 0.0f};

        // Load the 4 B fragments (one per cg) of k-step kt into dst.
        auto loadBF = [&](short8 (&dst)[4], int buf, int kt) {
            #pragma unroll
            for (int cg = 0; cg < 4; ++cg)
                dst[cg] = *(const short8*)(
                    &Bs[buf][(wc * 16 + cg * 4 + kt) * 512 + lane * 8]);
        };
        // 16 MFMAs of one k-step from a register fragment group.
        auto mfma16 = [&](floatx4 (&ac)[4][4], const short8 (&bf)[4], int hkt) {
            #pragma unroll
            for (int cg = 0; cg < 4; ++cg)
                #pragma unroll
                for (int rg = 0; rg < 4; ++rg)
                    ac[rg][cg] = __builtin_amdgcn_mfma_f32_16x16x32_bf16(
                        a[rg][hkt], bf[cg], ac[rg][cg], 0, 0, 0);
        };

        // One half-K body, software-pipelined over named register groups:
        // loads for kt+1 issue before kt's MFMAs (~310 cyc cover per batch).
        auto compHalf = [&](int buf, int h) {
            short8 bfA[4], bfB[4];
            loadBF(bfA, buf, 0);
            loadBF(bfB, buf, 1);
            mfma16(acc, bfA, h * 4 + 0);
            loadBF(bfA, buf, 2);
            mfma16(acc, bfB, h * 4 + 1);
            loadBF(bfB, buf, 3);
            mfma16(acc, bfA, h * 4 + 2);
            mfma16(acc, bfB, h * 4 + 3);
        };

        __syncthreads();           // drains (ct, h=0) DMA
        stageB(1, ybase, 1);       // prefetch (ct, h=1) into buf 1
        compHalf(0, 0);

        __syncthreads();           // drains (ct, h=1) DMA; all reads of buf0 done
        if (ct < 3)
            stageB(0, ybase + 32768, 0);  // prefetch (ct+1, h=0) into buf 0
        compHalf(1, 1);

        // Fold this col-tile into register-carried row min/max.
        #pragma unroll
        for (int rg = 0; rg < 4; ++rg)
            #pragma unroll
            for (int cg = 0; cg < 4; ++cg)
                #pragma unroll
                for (int r = 0; r < 4; ++r) {
                    float m = acc[rg][cg][r];
                    mn4[rg][r] = fminf(mn4[rg][r], m);
                    mx4[rg][r] = fmaxf(mx4[rg][r], m);
                }

        ybase += 32768;  // loop-carried: blocks cross-ct hoisting
    }

    // Single epilogue: quad-lane reduce, eval C twice (quasiconcavity),
    // fire-and-forget atomicMin (no read guard -- R3 post-mortem).
    #pragma unroll
    for (int rg = 0; rg < 4; ++rg) {
        #pragma unroll
        for (int r = 0; r < 4; ++r) {
            float mn = mn4[rg][r];
            float mx = mx4[rg][r];
            #pragma unroll
            for (int mofs = 1; mofs < 16; mofs <<= 1) {
                mn = fminf(mn, __shfl_xor(mn, mofs, 64));
                mx = fmaxf(mx, __shfl_xor(mx, mofs, 64));
            }
            if (lm == 0) {
                float cmin = fminf(c_of_m(mn), c_of_m(mx));
                int row = rowStart + wr * 64 + rg * 16 + lq * 4 + r;
                atomicMinFloat(&out[row], cmin);
            }
        }
    }
}

extern "C" void kernel_launch(void* const* d_in, const int* in_sizes, int n_in,
                              void* d_out, int out_size, void* d_ws, size_t ws_size,
                              hipStream_t stream) {
    const float* Ex = (const float*)d_in[0];
    const float* Ey = (const float*)d_in[1];
    float* out = (float*)d_out;
    u16* Xs = (u16*)d_ws;                // 4 MB, panel layout
    u16* Ys = Xs + (size_t)NROWS * DIM;  // 4 MB, panel layout

    hipLaunchKernelGGL(normalize_kernel, dim3(NROWS / 4, 2), dim3(256), 0, stream,
                       Ex, Ey, Xs, Ys, out);
    hipLaunchKernelGGL(gemm_min_kernel, dim3(64 * 16), dim3(256), 0, stream,
                       Xs, Ys, out);
}

// Round 14
// 103.321 us; speedup vs baseline: 1.8830x; 1.0094x over previous
//
#include <hip/hip_runtime.h>
#include <hip/hip_bf16.h>

typedef unsigned short u16;
typedef __attribute__((ext_vector_type(8))) short short8;
typedef __attribute__((ext_vector_type(4))) float floatx4;

#define NROWS 8192
#define DIM 256

__device__ __forceinline__ void atomicMinFloat(float* addr, float val) {
    if (val >= 0.0f) {
        atomicMin((int*)addr, __float_as_int(val));
    } else {
        atomicMax((unsigned int*)addr, __float_as_uint(val));
    }
}

__device__ __forceinline__ u16 f32_to_bf16_rne(float x) {
    unsigned int u = __float_as_uint(x);
    unsigned int r = (u + 0x7fffu + ((u >> 16) & 1u)) >> 16;
    return (u16)r;
}

// C(M) = -logp * exp(logp); quasiconcave in M => rowmin = min(C(minM), C(maxM)).
__device__ __forceinline__ float c_of_m(float m) {
    const float INV_SIG = 1.0f / 0.3f;
    const float KC = 0.28503427f;  // -ln(0.3) - 0.5*ln(2*pi)
    float z = (m - 1.0f) * INV_SIG;
    float logp = fmaf(-0.5f * z, z, KC);
    return -logp * __expf(logp);
}

// 16B async DMA global -> LDS. LDS dest is wave-uniform base + lane*16.
__device__ __forceinline__ void load16(const u16* g, u16* l) {
    __builtin_amdgcn_global_load_lds(
        (__attribute__((address_space(1))) void*)g,
        (__attribute__((address_space(3))) void*)l, 16, 0, 0);
}

// Normalize rows (L2-norm clamped at 1e-8), wave per row, float4 loads.
// BOTH X and Y are written in MFMA fragment ("panel") layout:
//   element (row r, k) -> flat[ ((p*8+kt)*64 + lq*16 + lm)*8 + j ]
//   p=r>>4, lm=r&15, kt=k>>5, lq=(k>>3)&3, j=k&7.
// A fragment load is then base + lane*16B: one coalesced dwordx4.
// Verified end-to-end R5/R11 (absmax 1.5e-5).
__global__ __launch_bounds__(256) void normalize_kernel(const float* __restrict__ Ex,
                                                        const float* __restrict__ Ey,
                                                        u16* __restrict__ Xs,
                                                        u16* __restrict__ Ys,
                                                        float* __restrict__ out) {
    const int t = threadIdx.x;
    const int ln = t & 63;
    const int row = blockIdx.x * 4 + (t >> 6);
    const float* src = (blockIdx.y == 0) ? Ex : Ey;
    u16* dst = (blockIdx.y == 0) ? Xs : Ys;

    float4 v = *(const float4*)(src + (size_t)row * DIM + ln * 4);
    float s = fmaf(v.x, v.x, fmaf(v.y, v.y, fmaf(v.z, v.z, v.w * v.w)));
    #pragma unroll
    for (int m = 32; m >= 1; m >>= 1) s += __shfl_xor(s, m, 64);
    float inv = 1.0f / fmaxf(sqrtf(s), 1e-8f);

    ushort4 o;
    o.x = f32_to_bf16_rne(v.x * inv);
    o.y = f32_to_bf16_rne(v.y * inv);
    o.z = f32_to_bf16_rne(v.z * inv);
    o.w = f32_to_bf16_rne(v.w * inv);

    const int p = row >> 4;
    const int lm = row & 15;
    const int kt = ln >> 3;
    const int lq = (ln >> 1) & 3;
    const int j4 = (ln & 1) * 4;
    const size_t off = ((size_t)((p * 8 + kt) * 64 + lq * 16 + lm)) * 8 + j4;
    *(ushort4*)(dst + off) = o;

    if (blockIdx.y == 0 && ln == 0) out[row] = __uint_as_float(0x7f800000u);  // +inf
}

// Block = 256 rows x 512 cols, 8 waves (4 row-groups x 2 col-groups),
// wave tile 64x64 (R11 micro-structure).
// A: each wave's 64 rows x full K from panel-layout Xs into registers
//    a[4][8] (128 VGPRs) -- loaded once, no A LDS traffic.
// B: half-K (128k x 512cols = 32 KB) LDS chunks, double-buffered, DMA-staged
//    (8 waves stage 4 x 1 KB units each). 8 barrier-drains per block.
// vs R11: BM 128->256 halves staged-B bytes per CU (1.25 -> 0.75 MB/CU
// incl. A) for the same MFMA work -- testing the vmem-service-floor theory
// of the 50 us plateau.
// __launch_bounds__(512, 2): cap = 256 regs/wave. R12's (512,4) capped at
// 128 and spilled 238 MB to scratch; usage here is ~240 so (512,2) fits.
// Grid 512: b&31 = row-tile (fixed A per XCD), b>>5 = colgroup.
__global__ void __launch_bounds__(512, 2)
gemm_min_kernel(const u16* __restrict__ Xs,
                const u16* __restrict__ Ys,
                float* __restrict__ out) {
    __shared__ u16 Bs[2][32 * 512];  // 2 x 32 KB

    const int tid = threadIdx.x;
    const int w = tid >> 6;      // 0..7
    const int lane = tid & 63;
    const int wr = w >> 1;       // 0..3 row-group
    const int wc = w & 1;        // 0..1 col-group
    const int lq = lane >> 4;
    const int lm = lane & 15;

    const int b = blockIdx.x;
    const int rowStart = (b & 31) * 256;
    const int rowPan0 = (b & 31) * 16 + wr * 4;
    const u16* ybase = Ys + (size_t)((b >> 5) * 32) * 4096;  // advances 32768/ct

    // --- A into registers, once (32 coalesced dwordx4 per lane) ---
    short8 a[4][8];
    #pragma unroll
    for (int rg = 0; rg < 4; ++rg)
        #pragma unroll
        for (int kt = 0; kt < 8; ++kt)
            a[rg][kt] = *(const short8*)(Xs + ((size_t)(rowPan0 + rg) * 8 + kt) * 512 + lane * 8);

    floatx4 mn4[4], mx4[4];
    #pragma unroll
    for (int rg = 0; rg < 4; ++rg) {
        mn4[rg] = (floatx4){3.4e38f, 3.4e38f, 3.4e38f, 3.4e38f};
        mx4[rg] = (floatx4){-3.4e38f, -3.4e38f, -3.4e38f, -3.4e38f};
    }

    // Stage one 32 KB B half-K chunk (8 panels x 4 kt-units of 1 KB) via DMA.
    // 8 waves stage 4 units each; unit u = (panel u>>2, kt u&3).
    auto stageB = [&](int buf, const u16* yb, int h) {
        #pragma unroll
        for (int i = 0; i < 4; ++i) {
            const int u = w * 4 + i;
            load16(yb + (u >> 2) * 4096 + (h * 4 + (u & 3)) * 512 + lane * 8,
                   &Bs[buf][u * 512]);
        }
    };

    stageB(0, ybase, 0);  // prologue: (ct=0, half 0)

    #pragma unroll 1
    for (int ct = 0; ct < 4; ++ct) {
        floatx4 acc[4][4];
        #pragma unroll
        for (int i = 0; i < 4; ++i)
            #pragma unroll
            for (int j = 0; j < 4; ++j)
                acc[i][j] = (floatx4){0.0f, 0.0f, 0.0f, 0.0f};

        // Load the 4 B fragments (one per cg) of k-step kt into dst.
        auto loadBF = [&](short8 (&dst)[4], int buf, int kt) {
            #pragma unroll
            for (int cg = 0; cg < 4; ++cg)
                dst[cg] = *(const short8*)(
                    &Bs[buf][(wc * 16 + cg * 4 + kt) * 512 + lane * 8]);
        };
        // 16 MFMAs of one k-step from a register fragment group.
        auto mfma16 = [&](floatx4 (&ac)[4][4], const short8 (&bf)[4], int hkt) {
            #pragma unroll
            for (int cg = 0; cg < 4; ++cg)
                #pragma unroll
                for (int rg = 0; rg < 4; ++rg)
                    ac[rg][cg] = __builtin_amdgcn_mfma_f32_16x16x32_bf16(
                        a[rg][hkt], bf[cg], ac[rg][cg], 0, 0, 0);
        };

        // One half-K body, software-pipelined over named register groups.
        auto compHalf = [&](int buf, int h) {
            short8 bfA[4], bfB[4];
            loadBF(bfA, buf, 0);
            loadBF(bfB, buf, 1);
            mfma16(acc, bfA, h * 4 + 0);
            loadBF(bfA, buf, 2);
            mfma16(acc, bfB, h * 4 + 1);
            loadBF(bfB, buf, 3);
            mfma16(acc, bfA, h * 4 + 2);
            mfma16(acc, bfB, h * 4 + 3);
        };

        __syncthreads();           // drains (ct, h=0) DMA
        stageB(1, ybase, 1);       // prefetch (ct, h=1) into buf 1
        compHalf(0, 0);

        __syncthreads();           // drains (ct, h=1) DMA; all reads of buf0 done
        if (ct < 3)
            stageB(0, ybase + 32768, 0);  // prefetch (ct+1, h=0) into buf 0
        compHalf(1, 1);

        // Fold this col-tile into register-carried row min/max.
        #pragma unroll
        for (int rg = 0; rg < 4; ++rg)
            #pragma unroll
            for (int cg = 0; cg < 4; ++cg)
                #pragma unroll
                for (int r = 0; r < 4; ++r) {
                    float m = acc[rg][cg][r];
                    mn4[rg][r] = fminf(mn4[rg][r], m);
                    mx4[rg][r] = fmaxf(mx4[rg][r], m);
                }

        ybase += 32768;  // loop-carried: blocks cross-ct hoisting
    }

    // Single epilogue: quad-lane reduce, eval C twice (quasiconcavity),
    // fire-and-forget atomicMin (no read guard -- R3 post-mortem).
    #pragma unroll
    for (int rg = 0; rg < 4; ++rg) {
        #pragma unroll
        for (int r = 0; r < 4; ++r) {
            float mn = mn4[rg][r];
            float mx = mx4[rg][r];
            #pragma unroll
            for (int mofs = 1; mofs < 16; mofs <<= 1) {
                mn = fminf(mn, __shfl_xor(mn, mofs, 64));
                mx = fmaxf(mx, __shfl_xor(mx, mofs, 64));
            }
            if (lm == 0) {
                float cmin = fminf(c_of_m(mn), c_of_m(mx));
                int row = rowStart + wr * 64 + rg * 16 + lq * 4 + r;
                atomicMinFloat(&out[row], cmin);
            }
        }
    }
}

extern "C" void kernel_launch(void* const* d_in, const int* in_sizes, int n_in,
                              void* d_out, int out_size, void* d_ws, size_t ws_size,
                              hipStream_t stream) {
    const float* Ex = (const float*)d_in[0];
    const float* Ey = (const float*)d_in[1];
    float* out = (float*)d_out;
    u16* Xs = (u16*)d_ws;                // 4 MB, panel layout
    u16* Ys = Xs + (size_t)NROWS * DIM;  // 4 MB, panel layout

    hipLaunchKernelGGL(normalize_kernel, dim3(NROWS / 4, 2), dim3(256), 0, stream,
                       Ex, Ey, Xs, Ys, out);
    hipLaunchKernelGGL(gemm_min_kernel, dim3(32 * 16), dim3(512), 0, stream,
                       Xs, Ys, out);
}

// Round 15
// 96.553 us; speedup vs baseline: 2.0150x; 1.0701x over previous
//
#include <hip/hip_runtime.h>
#include <hip/hip_bf16.h>

typedef unsigned short u16;
typedef __attribute__((ext_vector_type(8))) short short8;
typedef __attribute__((ext_vector_type(4))) float floatx4;

#define NROWS 8192
#define DIM 256

__device__ __forceinline__ void atomicMinFloat(float* addr, float val) {
    if (val >= 0.0f) {
        atomicMin((int*)addr, __float_as_int(val));
    } else {
        atomicMax((unsigned int*)addr, __float_as_uint(val));
    }
}

__device__ __forceinline__ u16 f32_to_bf16_rne(float x) {
    unsigned int u = __float_as_uint(x);
    unsigned int r = (u + 0x7fffu + ((u >> 16) & 1u)) >> 16;
    return (u16)r;
}

// C(M) = -logp * exp(logp); quasiconcave in M => rowmin = min(C(minM), C(maxM)).
__device__ __forceinline__ float c_of_m(float m) {
    const float INV_SIG = 1.0f / 0.3f;
    const float KC = 0.28503427f;  // -ln(0.3) - 0.5*ln(2*pi)
    float z = (m - 1.0f) * INV_SIG;
    float logp = fmaf(-0.5f * z, z, KC);
    return -logp * __expf(logp);
}

// 16B async DMA global -> LDS. LDS dest is wave-uniform base + lane*16.
__device__ __forceinline__ void load16(const u16* g, u16* l) {
    __builtin_amdgcn_global_load_lds(
        (__attribute__((address_space(1))) void*)g,
        (__attribute__((address_space(3))) void*)l, 16, 0, 0);
}

// Normalize rows (L2-norm clamped at 1e-8), wave per row, float4 loads.
// BOTH X and Y are written in MFMA fragment ("panel") layout:
//   element (row r, k) -> flat[ ((p*8+kt)*64 + lq*16 + lm)*8 + j ]
//   p=r>>4, lm=r&15, kt=k>>5, lq=(k>>3)&3, j=k&7.
// A fragment load is then base + lane*16B: one coalesced dwordx4.
// Verified end-to-end R5/R11/R14 (absmax 1.5e-5).
__global__ __launch_bounds__(256) void normalize_kernel(const float* __restrict__ Ex,
                                                        const float* __restrict__ Ey,
                                                        u16* __restrict__ Xs,
                                                        u16* __restrict__ Ys,
                                                        float* __restrict__ out) {
    const int t = threadIdx.x;
    const int ln = t & 63;
    const int row = blockIdx.x * 4 + (t >> 6);
    const float* src = (blockIdx.y == 0) ? Ex : Ey;
    u16* dst = (blockIdx.y == 0) ? Xs : Ys;

    float4 v = *(const float4*)(src + (size_t)row * DIM + ln * 4);
    float s = fmaf(v.x, v.x, fmaf(v.y, v.y, fmaf(v.z, v.z, v.w * v.w)));
    #pragma unroll
    for (int m = 32; m >= 1; m >>= 1) s += __shfl_xor(s, m, 64);
    float inv = 1.0f / fmaxf(sqrtf(s), 1e-8f);

    ushort4 o;
    o.x = f32_to_bf16_rne(v.x * inv);
    o.y = f32_to_bf16_rne(v.y * inv);
    o.z = f32_to_bf16_rne(v.z * inv);
    o.w = f32_to_bf16_rne(v.w * inv);

    const int p = row >> 4;
    const int lm = row & 15;
    const int kt = ln >> 3;
    const int lq = (ln >> 1) & 3;
    const int j4 = (ln & 1) * 4;
    const size_t off = ((size_t)((p * 8 + kt) * 64 + lq * 16 + lm)) * 8 + j4;
    *(ushort4*)(dst + off) = o;

    if (blockIdx.y == 0 && ln == 0) out[row] = __uint_as_float(0x7f800000u);  // +inf
}

// Block = 512 rows x 512 cols, 512 threads = 8 waves, EACH wave a distinct
// 64-row group (zero A duplication). All waves share the same 64-col tile
// per ct (B broadcast from LDS), sweeping 8 col-tiles.
// A: per wave 64 rows x full K from panel-layout Xs into a[4][8] (128 VGPR),
//    loaded once -- per-CU A traffic 256 KB, no LDS, no duplication.
// B: per ct one 64col x 256k tile (32 KB) DMA-staged, double-buffered
//    (64 KB LDS); ct+1 prefetch leads its barrier by a full ct body
//    (~2500 cyc of MFMA issue >> DMA latency) -> drains are cheap even at
//    1 block/CU. Per-CU B traffic 256 KB.
// Total staged bytes 0.5 MB/CU (R11 1.5 -> R14 1.0 -> here 0.5), attacking
// the measured ~10 B/cyc/CU vmem service floor.
// Grid 256 (1 block/CU): b&15 = row-tile, b>>4 = col-group.
__global__ void __launch_bounds__(512, 2)
gemm_min_kernel(const u16* __restrict__ Xs,
                const u16* __restrict__ Ys,
                float* __restrict__ out) {
    __shared__ u16 Bs[2][32 * 512];  // 2 x 32 KB

    const int tid = threadIdx.x;
    const int w = tid >> 6;      // 0..7 row-group
    const int lane = tid & 63;
    const int lq = lane >> 4;
    const int lm = lane & 15;

    const int b = blockIdx.x;
    const int rowStart = (b & 15) * 512;
    const int rowPan0 = (b & 15) * 32 + w * 4;
    const u16* ybase = Ys + (size_t)((b >> 4) * 32) * 4096;  // advances 16384/ct

    // --- A into registers, once (32 coalesced dwordx4 per lane, no dup) ---
    short8 a[4][8];
    #pragma unroll
    for (int rg = 0; rg < 4; ++rg)
        #pragma unroll
        for (int kt = 0; kt < 8; ++kt)
            a[rg][kt] = *(const short8*)(Xs + ((size_t)(rowPan0 + rg) * 8 + kt) * 512 + lane * 8);

    floatx4 mn4[4], mx4[4];
    #pragma unroll
    for (int rg = 0; rg < 4; ++rg) {
        mn4[rg] = (floatx4){3.4e38f, 3.4e38f, 3.4e38f, 3.4e38f};
        mx4[rg] = (floatx4){-3.4e38f, -3.4e38f, -3.4e38f, -3.4e38f};
    }

    // Stage one 64col x 256k B tile (32 KB = 32 x 1 KB units) via DMA.
    // 8 waves x 4 units; unit u -> (panel u>>3, kt u&7); LDS slot u*512 so
    // fragment reads are Bs[(cg*8+kt)*512 + lane*8] (b128, conflict-free).
    auto stageB = [&](int buf, const u16* yb) {
        #pragma unroll
        for (int i = 0; i < 4; ++i) {
            const int u = w * 4 + i;
            load16(yb + (u >> 3) * 4096 + (u & 7) * 512 + lane * 8,
                   &Bs[buf][u * 512]);
        }
    };

    stageB(0, ybase);  // prologue: ct=0 B tile

    #pragma unroll 1
    for (int ct = 0; ct < 8; ++ct) {
        const int buf = ct & 1;

        floatx4 acc[4][4];
        #pragma unroll
        for (int i = 0; i < 4; ++i)
            #pragma unroll
            for (int j = 0; j < 4; ++j)
                acc[i][j] = (floatx4){0.0f, 0.0f, 0.0f, 0.0f};

        __syncthreads();           // drains ct's B DMA
        if (ct < 7)
            stageB(buf ^ 1, ybase + 16384);  // prefetch ct+1 (full body of lead)

        // Full-K compute on this 64x64-per-wave col-tile.
        #pragma unroll
        for (int kt = 0; kt < 8; ++kt) {
            short8 bf[4];
            #pragma unroll
            for (int cg = 0; cg < 4; ++cg)
                bf[cg] = *(const short8*)(&Bs[buf][(cg * 8 + kt) * 512 + lane * 8]);
            #pragma unroll
            for (int cg = 0; cg < 4; ++cg)
                #pragma unroll
                for (int rg = 0; rg < 4; ++rg)
                    acc[rg][cg] = __builtin_amdgcn_mfma_f32_16x16x32_bf16(
                        a[rg][kt], bf[cg], acc[rg][cg], 0, 0, 0);
        }

        // Fold this col-tile into register-carried row min/max.
        #pragma unroll
        for (int rg = 0; rg < 4; ++rg)
            #pragma unroll
            for (int cg = 0; cg < 4; ++cg)
                #pragma unroll
                for (int r = 0; r < 4; ++r) {
                    float m = acc[rg][cg][r];
                    mn4[rg][r] = fminf(mn4[rg][r], m);
                    mx4[rg][r] = fmaxf(mx4[rg][r], m);
                }

        ybase += 16384;  // loop-carried: blocks cross-ct hoisting
    }

    // Single epilogue: quad-lane reduce, eval C twice (quasiconcavity),
    // fire-and-forget atomicMin (no read guard -- R3 post-mortem).
    #pragma unroll
    for (int rg = 0; rg < 4; ++rg) {
        #pragma unroll
        for (int r = 0; r < 4; ++r) {
            float mn = mn4[rg][r];
            float mx = mx4[rg][r];
            #pragma unroll
            for (int mofs = 1; mofs < 16; mofs <<= 1) {
                mn = fminf(mn, __shfl_xor(mn, mofs, 64));
                mx = fmaxf(mx, __shfl_xor(mx, mofs, 64));
            }
            if (lm == 0) {
                float cmin = fminf(c_of_m(mn), c_of_m(mx));
                int row = rowStart + w * 64 + rg * 16 + lq * 4 + r;
                atomicMinFloat(&out[row], cmin);
            }
        }
    }
}

extern "C" void kernel_launch(void* const* d_in, const int* in_sizes, int n_in,
                              void* d_out, int out_size, void* d_ws, size_t ws_size,
                              hipStream_t stream) {
    const float* Ex = (const float*)d_in[0];
    const float* Ey = (const float*)d_in[1];
    float* out = (float*)d_out;
    u16* Xs = (u16*)d_ws;                // 4 MB, panel layout
    u16* Ys = Xs + (size_t)NROWS * DIM;  // 4 MB, panel layout

    hipLaunchKernelGGL(normalize_kernel, dim3(NROWS / 4, 2), dim3(256), 0, stream,
                       Ex, Ey, Xs, Ys, out);
    hipLaunchKernelGGL(gemm_min_kernel, dim3(16 * 16), dim3(512), 0, stream,
                       Xs, Ys, out);
}

// Round 16
// 94.983 us; speedup vs baseline: 2.0483x; 1.0165x over previous
//
#include <hip/hip_runtime.h>
#include <hip/hip_bf16.h>

typedef unsigned short u16;
typedef __attribute__((ext_vector_type(8))) short short8;
typedef __attribute__((ext_vector_type(4))) float floatx4;

#define NROWS 8192
#define DIM 256

__device__ __forceinline__ void atomicMinFloat(float* addr, float val) {
    if (val >= 0.0f) {
        atomicMin((int*)addr, __float_as_int(val));
    } else {
        atomicMax((unsigned int*)addr, __float_as_uint(val));
    }
}

__device__ __forceinline__ u16 f32_to_bf16_rne(float x) {
    unsigned int u = __float_as_uint(x);
    unsigned int r = (u + 0x7fffu + ((u >> 16) & 1u)) >> 16;
    return (u16)r;
}

// C(M) = -logp * exp(logp); quasiconcave in M => rowmin = min(C(minM), C(maxM)).
__device__ __forceinline__ float c_of_m(float m) {
    const float INV_SIG = 1.0f / 0.3f;
    const float KC = 0.28503427f;  // -ln(0.3) - 0.5*ln(2*pi)
    float z = (m - 1.0f) * INV_SIG;
    float logp = fmaf(-0.5f * z, z, KC);
    return -logp * __expf(logp);
}

// 16B async DMA global -> LDS. LDS dest is wave-uniform base + lane*16.
__device__ __forceinline__ void load16(const u16* g, u16* l) {
    __builtin_amdgcn_global_load_lds(
        (__attribute__((address_space(1))) void*)g,
        (__attribute__((address_space(3))) void*)l, 16, 0, 0);
}

// Normalize rows (L2-norm clamped at 1e-8), wave per row, float4 loads.
// BOTH X and Y are written in MFMA fragment ("panel") layout:
//   element (row r, k) -> flat[ ((p*8+kt)*64 + lq*16 + lm)*8 + j ]
//   p=r>>4, lm=r&15, kt=k>>5, lq=(k>>3)&3, j=k&7.
// A fragment load is then base + lane*16B: one coalesced dwordx4.
// Verified end-to-end R5/R11/R14/R15 (absmax 1.5e-5).
__global__ __launch_bounds__(256) void normalize_kernel(const float* __restrict__ Ex,
                                                        const float* __restrict__ Ey,
                                                        u16* __restrict__ Xs,
                                                        u16* __restrict__ Ys,
                                                        float* __restrict__ out) {
    const int t = threadIdx.x;
    const int ln = t & 63;
    const int row = blockIdx.x * 4 + (t >> 6);
    const float* src = (blockIdx.y == 0) ? Ex : Ey;
    u16* dst = (blockIdx.y == 0) ? Xs : Ys;

    float4 v = *(const float4*)(src + (size_t)row * DIM + ln * 4);
    float s = fmaf(v.x, v.x, fmaf(v.y, v.y, fmaf(v.z, v.z, v.w * v.w)));
    #pragma unroll
    for (int m = 32; m >= 1; m >>= 1) s += __shfl_xor(s, m, 64);
    float inv = 1.0f / fmaxf(sqrtf(s), 1e-8f);

    ushort4 o;
    o.x = f32_to_bf16_rne(v.x * inv);
    o.y = f32_to_bf16_rne(v.y * inv);
    o.z = f32_to_bf16_rne(v.z * inv);
    o.w = f32_to_bf16_rne(v.w * inv);

    const int p = row >> 4;
    const int lm = row & 15;
    const int kt = ln >> 3;
    const int lq = (ln >> 1) & 3;
    const int j4 = (ln & 1) * 4;
    const size_t off = ((size_t)((p * 8 + kt) * 64 + lq * 16 + lm)) * 8 + j4;
    *(ushort4*)(dst + off) = o;

    if (blockIdx.y == 0 && ln == 0) out[row] = __uint_as_float(0x7f800000u);  // +inf
}

// Block = 512 rows x 512 cols, 512 threads = 8 waves, each wave a distinct
// 64-row group (zero A duplication); all waves share each 64-col B tile.
// R16 change vs R15: the A prologue (256 KB/CU, ~10 us serialized at
// 1 block/CU) is overlapped -- B0's DMA issues FIRST (hides under A k0/k1
// loads), and A kt=2..7 (24 loads) issue after the barrier, pipelined
// against ct=0's MFMA stream via vmcnt. cts 1..7 identical to R15.
// Staged traffic stays 0.5 MB/CU (the R11->R15 lever: 1.5->1.0->0.5).
// Grid 256 (1 block/CU): b&15 = row-tile, b>>4 = col-group.
__global__ void __launch_bounds__(512, 2)
gemm_min_kernel(const u16* __restrict__ Xs,
                const u16* __restrict__ Ys,
                float* __restrict__ out) {
    __shared__ u16 Bs[2][32 * 512];  // 2 x 32 KB

    const int tid = threadIdx.x;
    const int w = tid >> 6;      // 0..7 row-group
    const int lane = tid & 63;
    const int lq = lane >> 4;
    const int lm = lane & 15;

    const int b = blockIdx.x;
    const int rowStart = (b & 15) * 512;
    const int rowPan0 = (b & 15) * 32 + w * 4;
    const u16* ybase = Ys + (size_t)((b >> 4) * 32) * 4096;  // advances 16384/ct

    // Stage one 64col x 256k B tile (32 KB = 32 x 1 KB units) via DMA.
    // 8 waves x 4 units; unit u -> (panel u>>3, kt u&7); LDS slot u*512 so
    // fragment reads are Bs[(cg*8+kt)*512 + lane*8] (b128, conflict-free).
    auto stageB = [&](int buf, const u16* yb) {
        #pragma unroll
        for (int i = 0; i < 4; ++i) {
            const int u = w * 4 + i;
            load16(yb + (u >> 3) * 4096 + (u & 7) * 512 + lane * 8,
                   &Bs[buf][u * 512]);
        }
    };

    short8 a[4][8];
    auto loadA = [&](int kt) {
        #pragma unroll
        for (int rg = 0; rg < 4; ++rg)
            a[rg][kt] = *(const short8*)(
                Xs + ((size_t)(rowPan0 + rg) * 8 + kt) * 512 + lane * 8);
    };

    floatx4 mn4[4], mx4[4];
    #pragma unroll
    for (int rg = 0; rg < 4; ++rg) {
        mn4[rg] = (floatx4){3.4e38f, 3.4e38f, 3.4e38f, 3.4e38f};
        mx4[rg] = (floatx4){-3.4e38f, -3.4e38f, -3.4e38f, -3.4e38f};
    }

    floatx4 acc[4][4];
    auto zeroAcc = [&]() {
        #pragma unroll
        for (int i = 0; i < 4; ++i)
            #pragma unroll
            for (int j = 0; j < 4; ++j)
                acc[i][j] = (floatx4){0.0f, 0.0f, 0.0f, 0.0f};
    };
    auto compute = [&](int buf) {
        #pragma unroll
        for (int kt = 0; kt < 8; ++kt) {
            short8 bf[4];
            #pragma unroll
            for (int cg = 0; cg < 4; ++cg)
                bf[cg] = *(const short8*)(&Bs[buf][(cg * 8 + kt) * 512 + lane * 8]);
            #pragma unroll
            for (int cg = 0; cg < 4; ++cg)
                #pragma unroll
                for (int rg = 0; rg < 4; ++rg)
                    acc[rg][cg] = __builtin_amdgcn_mfma_f32_16x16x32_bf16(
                        a[rg][kt], bf[cg], acc[rg][cg], 0, 0, 0);
        }
    };
    auto fold = [&]() {
        #pragma unroll
        for (int rg = 0; rg < 4; ++rg)
            #pragma unroll
            for (int cg = 0; cg < 4; ++cg)
                #pragma unroll
                for (int r = 0; r < 4; ++r) {
                    float m = acc[rg][cg][r];
                    mn4[rg][r] = fminf(mn4[rg][r], m);
                    mx4[rg][r] = fmaxf(mx4[rg][r], m);
                }
    };

    // --- ct = 0, peeled: overlap A prologue with B0 DMA + early compute ---
    stageB(0, ybase);        // B0 DMA first (hides under the A k0/k1 loads)
    loadA(0);
    loadA(1);
    __syncthreads();         // drains B0 DMA (+ the 8 early A loads)
    stageB(1, ybase + 16384);  // prefetch ct=1
    // Remaining A loads: issued ahead of ct=0's MFMA stream; vmcnt pipelining
    // drains them behind the first k-steps (exposure ~1 k-step, not ~25k cyc).
    loadA(2); loadA(3); loadA(4); loadA(5); loadA(6); loadA(7);
    zeroAcc();
    compute(0);
    fold();
    ybase += 16384;

    // --- cts 1..7: steady state (R15 structure) ---
    #pragma unroll 1
    for (int ct = 1; ct < 8; ++ct) {
        const int buf = ct & 1;
        zeroAcc();
        __syncthreads();           // drains ct's B DMA
        if (ct < 7)
            stageB(buf ^ 1, ybase + 16384);  // prefetch ct+1
        compute(buf);
        fold();
        ybase += 16384;  // loop-carried: blocks cross-ct hoisting
    }

    // Single epilogue: quad-lane reduce, eval C twice (quasiconcavity),
    // fire-and-forget atomicMin (no read guard -- R3 post-mortem).
    #pragma unroll
    for (int rg = 0; rg < 4; ++rg) {
        #pragma unroll
        for (int r = 0; r < 4; ++r) {
            float mn = mn4[rg][r];
            float mx = mx4[rg][r];
            #pragma unroll
            for (int mofs = 1; mofs < 16; mofs <<= 1) {
                mn = fminf(mn, __shfl_xor(mn, mofs, 64));
                mx = fmaxf(mx, __shfl_xor(mx, mofs, 64));
            }
            if (lm == 0) {
                float cmin = fminf(c_of_m(mn), c_of_m(mx));
                int row = rowStart + w * 64 + rg * 16 + lq * 4 + r;
                atomicMinFloat(&out[row], cmin);
            }
        }
    }
}

extern "C" void kernel_launch(void* const* d_in, const int* in_sizes, int n_in,
                              void* d_out, int out_size, void* d_ws, size_t ws_size,
                              hipStream_t stream) {
    const float* Ex = (const float*)d_in[0];
    const float* Ey = (const float*)d_in[1];
    float* out = (float*)d_out;
    u16* Xs = (u16*)d_ws;                // 4 MB, panel layout
    u16* Ys = Xs + (size_t)NROWS * DIM;  // 4 MB, panel layout

    hipLaunchKernelGGL(normalize_kernel, dim3(NROWS / 4, 2), dim3(256), 0, stream,
                       Ex, Ey, Xs, Ys, out);
    hipLaunchKernelGGL(gemm_min_kernel, dim3(16 * 16), dim3(512), 0, stream,
                       Xs, Ys, out);
}